// Round 2
// baseline (1307.973 us; speedup 1.0000x reference)
//
#include <hip/hip_runtime.h>
#include <hip/hip_bf16.h>

// ---------------- problem constants ----------------
#define T_TOK   8192
#define H_DIM   1024
#define FFN_DIM 4096
#define NE      8
#define BM      128
#define BN      128
#define BK      32
#define MAX_RB  (T_TOK * 2 / BM + NE)   // 136
#define MAX_ROWS (MAX_RB * BM)          // 17408

typedef unsigned short u16;
typedef u16   u16x8  __attribute__((ext_vector_type(8)));
typedef __bf16 bf16x8 __attribute__((ext_vector_type(8)));
typedef float f32x4  __attribute__((ext_vector_type(4)));

// ---------------- workspace layout (bytes) ----------------
// meta ints: [0..7] counts, [8..15] fill, [16..24] padded offsets, [25] total_rows, [26] total_rb
#define META_OFF   ((size_t)0)
#define PICKE_OFF  ((size_t)1024)
#define PICKW_OFF  (PICKE_OFF + (size_t)T_TOK * 2 * 4)
#define PERM_OFF   (PICKW_OFF + (size_t)T_TOK * 2 * 4)
#define WSORT_OFF  (PERM_OFF  + (size_t)MAX_ROWS * 4)
#define XBF_OFF    (WSORT_OFF + (size_t)MAX_ROWS * 4)               // 271360
#define W1T_OFF    (XBF_OFF + (size_t)T_TOK * H_DIM * 2)            // +16 MB
#define W3T_OFF    (W1T_OFF + (size_t)NE * FFN_DIM * H_DIM * 2)     // +64 MB each
#define W2T_OFF    (W3T_OFF + (size_t)NE * FFN_DIM * H_DIM * 2)
#define HBUF_OFF   (W2T_OFF + (size_t)NE * FFN_DIM * H_DIM * 2)
#define YPART_OFF  W1T_OFF   // alias: W1T (64MB) dead after gemm1; ypart fp32 (64MB) born in gemm2

__device__ __forceinline__ u16 f2bf(float f) {
    unsigned u = __builtin_bit_cast(unsigned, f);
    unsigned r = u + 0x7fffu + ((u >> 16) & 1u);   // RNE
    return (u16)(r >> 16);
}
__device__ __forceinline__ float bf2f(u16 u) {
    unsigned v = ((unsigned)u) << 16;
    return __builtin_bit_cast(float, v);
}

// ---------------- tiny init ----------------
__global__ void init_k(int* meta) {
    if (threadIdx.x < 256) meta[threadIdx.x] = 0;
}

// ---------------- x: fp32 -> bf16, same layout ----------------
__global__ void cvt_x_k(const float* __restrict__ src, u16* __restrict__ dst) {
    int i = blockIdx.x * 256 + threadIdx.x;   // one u16x8 per thread
    f32x4 a = *(const f32x4*)(src + (size_t)i * 8);
    f32x4 b = *(const f32x4*)(src + (size_t)i * 8 + 4);
    u16x8 o;
#pragma unroll
    for (int j = 0; j < 4; j++) { o[j] = f2bf(a[j]); o[4 + j] = f2bf(b[j]); }
    *(u16x8*)(dst + (size_t)i * 8) = o;
}

// ---------------- transpose+convert: dst_bf16[C][R] = src_f32[R][C], per expert ----------------
__global__ void transpose_cvt_k(const float* __restrict__ src, u16* __restrict__ dst, int R, int C) {
    __shared__ u16 Lt[64 * 72];
    int bx = blockIdx.x, by = blockIdx.y, e = blockIdx.z;
    const float* s = src + (size_t)e * R * C + (size_t)(by * 64) * C + bx * 64;
    u16* d = dst + (size_t)e * R * C + (size_t)(bx * 64) * R + by * 64;
    int tid = threadIdx.x;
#pragma unroll
    for (int o = tid; o < 512; o += 256) {
        int r = o >> 3, cc = o & 7;
        const float* sp = s + (size_t)r * C + cc * 8;
        f32x4 f0 = *(const f32x4*)sp;
        f32x4 f1 = *(const f32x4*)(sp + 4);
        u16x8 v;
#pragma unroll
        for (int j = 0; j < 4; j++) { v[j] = f2bf(f0[j]); v[4 + j] = f2bf(f1[j]); }
        int cs = (cc ^ ((r >> 3) & 7)) & 7;
        *(u16x8*)&Lt[r * 72 + cs * 8] = v;
    }
    __syncthreads();
#pragma unroll
    for (int o = tid; o < 512; o += 256) {
        int cl = o >> 3, rc = o & 7;
        u16x8 w;
#pragma unroll
        for (int j = 0; j < 8; j++) {
            int rr = rc * 8 + j;
            w[j] = Lt[rr * 72 + ((((cl >> 3) ^ rc) & 7) * 8) + (cl & 7)];
        }
        *(u16x8*)(d + (size_t)cl * R + rc * 8) = w;
    }
}

// ---------------- router: fp32 logits, top-2, picks ----------------
__global__ void router_k(const float* __restrict__ x, const float* __restrict__ gw,
                         float* __restrict__ out_logits, int* __restrict__ meta,
                         int* __restrict__ picke, float* __restrict__ pickw) {
    __shared__ float G[NE * H_DIM];   // 32 KB
    int tid = threadIdx.x;
#pragma unroll
    for (int o = tid; o < 2048; o += 256)
        *(f32x4*)&G[o * 4] = *(const f32x4*)(gw + o * 4);
    __syncthreads();

    int wave = tid >> 6, lane = tid & 63;
    int t = blockIdx.x * 4 + wave;
    const float* xr = x + (size_t)t * H_DIM + lane * 16;
    f32x4 v0 = *(const f32x4*)xr,       v1 = *(const f32x4*)(xr + 4);
    f32x4 v2 = *(const f32x4*)(xr + 8), v3 = *(const f32x4*)(xr + 12);

    float acc[NE];
#pragma unroll
    for (int e = 0; e < NE; e++) {
        const float* gr = &G[e * H_DIM + lane * 16];
        f32x4 g0 = *(const f32x4*)gr,       g1 = *(const f32x4*)(gr + 4);
        f32x4 g2 = *(const f32x4*)(gr + 8), g3 = *(const f32x4*)(gr + 12);
        float a = 0.f;
#pragma unroll
        for (int j = 0; j < 4; j++) {
            a += v0[j] * g0[j]; a += v1[j] * g1[j];
            a += v2[j] * g2[j]; a += v3[j] * g3[j];
        }
        acc[e] = a;
    }
#pragma unroll
    for (int e = 0; e < NE; e++)
#pragma unroll
        for (int off = 32; off > 0; off >>= 1) acc[e] += __shfl_xor(acc[e], off);

    if (lane < NE) out_logits[(size_t)t * NE + lane] = acc[lane];
    if (lane == 0) {
        int a1 = 0;
#pragma unroll
        for (int e = 1; e < NE; e++) if (acc[e] > acc[a1]) a1 = e;
        int a2 = (a1 == 0) ? 1 : 0;
#pragma unroll
        for (int e = 0; e < NE; e++) if (e != a1 && acc[e] > acc[a2]) a2 = e;
        float p2 = __expf(acc[a2] - acc[a1]);
        float s = 1.f + p2;
        picke[t * 2] = a1;  picke[t * 2 + 1] = a2;
        pickw[t * 2] = 1.f / s;  pickw[t * 2 + 1] = p2 / s;
        atomicAdd(&meta[a1], 1);
        atomicAdd(&meta[a2], 1);
    }
}

// ---------------- schedule: padded segment offsets + default fill ----------------
__global__ void sched_k(int* meta, int* perm, float* wsort) {
    if (threadIdx.x == 0) {
        int o = 0;
        for (int e = 0; e < NE; e++) {
            meta[16 + e] = o;
            o += ((meta[e] + BM - 1) / BM) * BM;
        }
        meta[16 + NE] = o;
        meta[25] = o;
        meta[26] = o / BM;
    }
    for (int i = threadIdx.x; i < MAX_ROWS; i += 256) { perm[i] = -1; wsort[i] = 0.f; }
}

// ---------------- scatter: sorted (token,slot) list ----------------
__global__ void scatter_k(int* meta, const int* __restrict__ picke,
                          const float* __restrict__ pickw,
                          int* __restrict__ perm, float* __restrict__ wsort) {
    int t = blockIdx.x * 256 + threadIdx.x;
#pragma unroll
    for (int k = 0; k < 2; k++) {
        int e = picke[t * 2 + k];
        int pos = meta[16 + e] + atomicAdd(&meta[8 + e], 1);
        perm[pos] = t * 2 + k;
        wsort[pos] = pickw[t * 2 + k];
    }
}

// ---------------- GEMM1: h = silu(X W1) * (X W3), gathered rows ----------------
__launch_bounds__(256, 2)
__global__ void gemm1_k(const u16* __restrict__ x, const u16* __restrict__ w1t,
                        const u16* __restrict__ w3t, u16* __restrict__ hbuf,
                        const int* __restrict__ meta, const int* __restrict__ perm) {
    int rb = blockIdx.y;
    if (rb >= meta[26]) return;
    int nb = blockIdx.x;
    int row0 = rb * BM;
    int e = 0;
#pragma unroll
    for (int i = 1; i < NE; i++) if (row0 >= meta[16 + i]) e = i;

    __shared__ u16 As[BM * BK], B1s[BN * BK], B3s[BN * BK];
    __shared__ int toks[BM];
    int tid = threadIdx.x;
    if (tid < BM) { int p = perm[row0 + tid]; toks[tid] = (p < 0) ? 0 : (p >> 1); }
    __syncthreads();

    int ar0 = tid >> 2, as0 = tid & 3;
    int ar1 = ar0 + 64;
    const u16* aptr0 = x + (size_t)toks[ar0] * H_DIM + as0 * 8;
    const u16* aptr1 = x + (size_t)toks[ar1] * H_DIM + as0 * 8;
    const u16* wb1 = w1t + (size_t)e * FFN_DIM * H_DIM + (size_t)(nb * BN) * H_DIM;
    const u16* wb3 = w3t + (size_t)e * FFN_DIM * H_DIM + (size_t)(nb * BN) * H_DIM;
    const u16* b1p0 = wb1 + (size_t)ar0 * H_DIM + as0 * 8;
    const u16* b1p1 = wb1 + (size_t)ar1 * H_DIM + as0 * 8;
    const u16* b3p0 = wb3 + (size_t)ar0 * H_DIM + as0 * 8;
    const u16* b3p1 = wb3 + (size_t)ar1 * H_DIM + as0 * 8;

    int aw0 = ar0 * BK + ((as0 ^ ((ar0 >> 1) & 3)) * 8);
    int aw1 = ar1 * BK + ((as0 ^ ((ar1 >> 1) & 3)) * 8);

    int wave = tid >> 6, lane = tid & 63, quad = lane >> 4, l16 = lane & 15;
    int wm = (wave >> 1) * 64, wn = (wave & 1) * 64;
    int aoff[4], boff[4];
#pragma unroll
    for (int i = 0; i < 4; i++) { int r = wm + i * 16 + l16; aoff[i] = r * BK + ((quad ^ ((r >> 1) & 3)) * 8); }
#pragma unroll
    for (int j = 0; j < 4; j++) { int n = wn + j * 16 + l16; boff[j] = n * BK + ((quad ^ ((n >> 1) & 3)) * 8); }

    f32x4 acc1[4][4], acc3[4][4];
    f32x4 zero = {0.f, 0.f, 0.f, 0.f};
#pragma unroll
    for (int i = 0; i < 4; i++)
#pragma unroll
        for (int j = 0; j < 4; j++) { acc1[i][j] = zero; acc3[i][j] = zero; }

    for (int k0 = 0; k0 < H_DIM; k0 += BK) {
        u16x8 a0 = *(const u16x8*)(aptr0 + k0);
        u16x8 a1 = *(const u16x8*)(aptr1 + k0);
        u16x8 c10 = *(const u16x8*)(b1p0 + k0);
        u16x8 c11 = *(const u16x8*)(b1p1 + k0);
        u16x8 c30 = *(const u16x8*)(b3p0 + k0);
        u16x8 c31 = *(const u16x8*)(b3p1 + k0);
        __syncthreads();
        *(u16x8*)&As[aw0] = a0;  *(u16x8*)&As[aw1] = a1;
        *(u16x8*)&B1s[aw0] = c10; *(u16x8*)&B1s[aw1] = c11;
        *(u16x8*)&B3s[aw0] = c30; *(u16x8*)&B3s[aw1] = c31;
        __syncthreads();
        bf16x8 af[4];
#pragma unroll
        for (int i = 0; i < 4; i++) af[i] = *(const bf16x8*)&As[aoff[i]];
#pragma unroll
        for (int jn = 0; jn < 4; jn++) {
            bf16x8 b1 = *(const bf16x8*)&B1s[boff[jn]];
            bf16x8 b3 = *(const bf16x8*)&B3s[boff[jn]];
#pragma unroll
            for (int i = 0; i < 4; i++) {
                acc1[i][jn] = __builtin_amdgcn_mfma_f32_16x16x32_bf16(af[i], b1, acc1[i][jn], 0, 0, 0);
                acc3[i][jn] = __builtin_amdgcn_mfma_f32_16x16x32_bf16(af[i], b3, acc3[i][jn], 0, 0, 0);
            }
        }
    }
#pragma unroll
    for (int i = 0; i < 4; i++)
#pragma unroll
        for (int jn = 0; jn < 4; jn++) {
            f32x4 c1 = acc1[i][jn], c3 = acc3[i][jn];
#pragma unroll
            for (int r = 0; r < 4; r++) {
                float v1 = c1[r];
                float hv = v1 / (1.f + __expf(-v1)) * c3[r];
                int rg = row0 + wm + i * 16 + quad * 4 + r;
                int col = nb * BN + wn + jn * 16 + l16;
                hbuf[(size_t)rg * FFN_DIM + col] = f2bf(hv);
            }
        }
}

// ---------------- GEMM2: ypart = weight * (h W2), scattered fp32 ----------------
__launch_bounds__(256, 2)
__global__ void gemm2_k(const u16* __restrict__ hbuf, const u16* __restrict__ w2t,
                        float* __restrict__ ypart, const int* __restrict__ meta,
                        const int* __restrict__ perm, const float* __restrict__ wsort) {
    int rb = blockIdx.y;
    if (rb >= meta[26]) return;
    int nb = blockIdx.x;  // 0..7
    int row0 = rb * BM;
    int e = 0;
#pragma unroll
    for (int i = 1; i < NE; i++) if (row0 >= meta[16 + i]) e = i;

    __shared__ u16 As[BM * BK], Bs[BN * BK];
    __shared__ int pe[BM];
    __shared__ float pw[BM];
    int tid = threadIdx.x;
    if (tid < BM) { pe[tid] = perm[row0 + tid]; pw[tid] = wsort[row0 + tid]; }
    __syncthreads();

    int ar0 = tid >> 2, as0 = tid & 3;
    int ar1 = ar0 + 64;
    const u16* aptr0 = hbuf + (size_t)(row0 + ar0) * FFN_DIM + as0 * 8;
    const u16* aptr1 = hbuf + (size_t)(row0 + ar1) * FFN_DIM + as0 * 8;
    const u16* wb = w2t + (size_t)e * H_DIM * FFN_DIM + (size_t)(nb * BN) * FFN_DIM;
    const u16* bp0 = wb + (size_t)ar0 * FFN_DIM + as0 * 8;
    const u16* bp1 = wb + (size_t)ar1 * FFN_DIM + as0 * 8;

    int aw0 = ar0 * BK + ((as0 ^ ((ar0 >> 1) & 3)) * 8);
    int aw1 = ar1 * BK + ((as0 ^ ((ar1 >> 1) & 3)) * 8);

    int wave = tid >> 6, lane = tid & 63, quad = lane >> 4, l16 = lane & 15;
    int wm = (wave >> 1) * 64, wn = (wave & 1) * 64;
    int aoff[4], boff[4];
#pragma unroll
    for (int i = 0; i < 4; i++) { int r = wm + i * 16 + l16; aoff[i] = r * BK + ((quad ^ ((r >> 1) & 3)) * 8); }
#pragma unroll
    for (int j = 0; j < 4; j++) { int n = wn + j * 16 + l16; boff[j] = n * BK + ((quad ^ ((n >> 1) & 3)) * 8); }

    f32x4 acc[4][4];
    f32x4 zero = {0.f, 0.f, 0.f, 0.f};
#pragma unroll
    for (int i = 0; i < 4; i++)
#pragma unroll
        for (int j = 0; j < 4; j++) acc[i][j] = zero;

    for (int k0 = 0; k0 < FFN_DIM; k0 += BK) {
        u16x8 a0 = *(const u16x8*)(aptr0 + k0);
        u16x8 a1 = *(const u16x8*)(aptr1 + k0);
        u16x8 b0 = *(const u16x8*)(bp0 + k0);
        u16x8 b1v = *(const u16x8*)(bp1 + k0);
        __syncthreads();
        *(u16x8*)&As[aw0] = a0; *(u16x8*)&As[aw1] = a1;
        *(u16x8*)&Bs[aw0] = b0; *(u16x8*)&Bs[aw1] = b1v;
        __syncthreads();
        bf16x8 af[4];
#pragma unroll
        for (int i = 0; i < 4; i++) af[i] = *(const bf16x8*)&As[aoff[i]];
#pragma unroll
        for (int jn = 0; jn < 4; jn++) {
            bf16x8 bf = *(const bf16x8*)&Bs[boff[jn]];
#pragma unroll
            for (int i = 0; i < 4; i++)
                acc[i][jn] = __builtin_amdgcn_mfma_f32_16x16x32_bf16(af[i], bf, acc[i][jn], 0, 0, 0);
        }
    }
#pragma unroll
    for (int i = 0; i < 4; i++)
#pragma unroll
        for (int jn = 0; jn < 4; jn++) {
            f32x4 c = acc[i][jn];
#pragma unroll
            for (int r = 0; r < 4; r++) {
                int rloc = wm + i * 16 + quad * 4 + r;
                int p = pe[rloc];
                if (p >= 0) {
                    int col = nb * BN + wn + jn * 16 + l16;
                    ypart[(size_t)p * H_DIM + col] = c[r] * pw[rloc];
                }
            }
        }
}

// ---------------- combine the two expert slots per token (fp32) ----------------
__global__ void combine_k(const float* __restrict__ ypart, float* __restrict__ y) {
    int c = blockIdx.x * 256 + threadIdx.x;   // one f32x4 per thread; T*H/4 total
    int t = c >> 8, cc = c & 255;             // H/4 = 256 chunks per row
    f32x4 a = *(const f32x4*)(ypart + (size_t)(t * 2) * H_DIM + cc * 4);
    f32x4 b = *(const f32x4*)(ypart + (size_t)(t * 2 + 1) * H_DIM + cc * 4);
    f32x4 o = a + b;
    *(f32x4*)(y + (size_t)t * H_DIM + cc * 4) = o;
}

extern "C" void kernel_launch(void* const* d_in, const int* in_sizes, int n_in,
                              void* d_out, int out_size, void* d_ws, size_t ws_size,
                              hipStream_t stream) {
    (void)in_sizes; (void)n_in; (void)out_size; (void)ws_size;
    const float* x  = (const float*)d_in[0];
    const float* gw = (const float*)d_in[1];
    const float* w1 = (const float*)d_in[2];
    const float* w2 = (const float*)d_in[3];
    const float* w3 = (const float*)d_in[4];
    float* out = (float*)d_out;
    char* ws = (char*)d_ws;

    int*   meta  = (int*)(ws + META_OFF);
    int*   picke = (int*)(ws + PICKE_OFF);
    float* pickw = (float*)(ws + PICKW_OFF);
    int*   perm  = (int*)(ws + PERM_OFF);
    float* wsort = (float*)(ws + WSORT_OFF);
    u16*   xbf   = (u16*)(ws + XBF_OFF);
    u16*   w1t   = (u16*)(ws + W1T_OFF);
    u16*   w3t   = (u16*)(ws + W3T_OFF);
    u16*   w2t   = (u16*)(ws + W2T_OFF);
    u16*   hbuf  = (u16*)(ws + HBUF_OFF);
    float* ypart = (float*)(ws + YPART_OFF);

    init_k<<<1, 256, 0, stream>>>(meta);
    cvt_x_k<<<T_TOK * H_DIM / 8 / 256, 256, 0, stream>>>(x, xbf);
    transpose_cvt_k<<<dim3(FFN_DIM / 64, H_DIM / 64, NE), 256, 0, stream>>>(w1, w1t, H_DIM, FFN_DIM);
    transpose_cvt_k<<<dim3(FFN_DIM / 64, H_DIM / 64, NE), 256, 0, stream>>>(w3, w3t, H_DIM, FFN_DIM);
    transpose_cvt_k<<<dim3(H_DIM / 64, FFN_DIM / 64, NE), 256, 0, stream>>>(w2, w2t, FFN_DIM, H_DIM);
    router_k<<<T_TOK / 4, 256, 0, stream>>>(x, gw, out + (size_t)T_TOK * H_DIM, meta, picke, pickw);
    sched_k<<<1, 256, 0, stream>>>(meta, perm, wsort);
    scatter_k<<<T_TOK / 256, 256, 0, stream>>>(meta, picke, pickw, perm, wsort);
    gemm1_k<<<dim3(FFN_DIM / BN, MAX_RB), 256, 0, stream>>>(xbf, w1t, w3t, hbuf, meta, perm);
    gemm2_k<<<dim3(H_DIM / BN, MAX_RB), 256, 0, stream>>>(hbuf, w2t, ypart, meta, perm, wsort);
    combine_k<<<T_TOK * H_DIM / 4 / 256, 256, 0, stream>>>(ypart, out);
}